// Round 11
// baseline (82.901 us; speedup 1.0000x reference)
//
#include <hip/hip_runtime.h>
#include <math.h>

// GaussianMixtureLoss — R11: AMPLIFIED PROBE (sacrificial measurement round).
// Inner j-loop repeated REP=8x (asm memory clobber per rep prevents hoisting),
// comb write scaled by 1/REP so the output is numerically identical.
// Purpose: push gm_main past the harness's 39us poison-fills so its rocprof
// counters (VALUBusy, SQ_LDS_BANK_CONFLICT, Occupancy, VGPR) become visible,
// and decode inner-loop time i = (T - 19.8)/7.
// Structure otherwise identical to R10.
#define BATCH 4
#define NPTS 4096
#define NMIX 4096
#define THREADS 256
#define PPB 16
#define PPT 8
#define SCH 128
#define MSTAGE 2048
#define PASSES (NMIX / MSTAGE)
#define MPT (MSTAGE / SCH)    // 16
#define NBLOCKS ((BATCH * NPTS) / PPB)  // 1024
#define REP 8

#define L2E 1.4426950408889634f
#define LN2 0.6931471805599453f
#define CONST_TERM 0.9189385332046727f
#define INV_COUNT (1.0f / (float)(BATCH * NPTS))
#define SEXP_SCALE 8388608.0f
#define SEXP_BIAS  1.06488094e9f

typedef float v2f __attribute__((ext_vector_type(2)));

__device__ __forceinline__ float fast_log2(float x) {
#if __has_builtin(__builtin_amdgcn_logf)
  return __builtin_amdgcn_logf(x);
#else
  return log2f(x);
#endif
}

__device__ __forceinline__ v2f sexp2_v2(v2f x) {
  v2f t = __builtin_elementwise_fma(
      x, (v2f){SEXP_SCALE, SEXP_SCALE}, (v2f){SEXP_BIAS, SEXP_BIAS});
  t = __builtin_elementwise_max(t, (v2f){0.f, 0.f});
  int ix = (int)t.x, iy = (int)t.y;
  v2f r;
  r.x = __builtin_bit_cast(float, ix);
  r.y = __builtin_bit_cast(float, iy);
  return r;
}

__global__ __launch_bounds__(THREADS) void gm_main(
    const float* __restrict__ pred, const float* __restrict__ gt,
    float* __restrict__ bsum) {
  __shared__ float4 gsh[MSTAGE];
  __shared__ float wpart[64];
  float* comb = (float*)gsh;

  const int t = threadIdx.x;
  const int b = blockIdx.x >> 8;
  const int n0 = (blockIdx.x & 255) * PPB;
  const int c = t >> 1;
  const int pi = (t & 1) * PPT;

  v2f px[4], py[4], pz[4], acc[4];
#pragma unroll
  for (int k = 0; k < 4; ++k) {
    const float* p = pred + ((size_t)(b * NPTS + n0 + pi + 2 * k)) * 3;
    px[k] = (v2f){p[0], p[3]};
    py[k] = (v2f){p[1], p[4]};
    pz[k] = (v2f){p[2], p[5]};
    acc[k] = (v2f){0.f, 0.f};
  }

  for (int q = 0; q < PASSES; ++q) {
    __syncthreads();
#pragma unroll
    for (int k2 = 0; k2 < MSTAGE / THREADS; ++k2) {
      int s = t + k2 * THREADS;
      const float* g = gt + ((size_t)(b * NMIX + q * MSTAGE + s)) * 3;
      float gx = g[0], gy = g[1], gz = g[2];
      gsh[s] = make_float4(L2E * gx, L2E * gy, L2E * gz,
                           -0.5f * L2E * (gx * gx + gy * gy + gz * gz));
    }
    __syncthreads();

#pragma unroll 1
    for (int rep = 0; rep < REP; ++rep) {
      asm volatile("" ::: "memory");  // force re-read of gsh each rep
#pragma unroll 2
      for (int j = 0; j < MPT; ++j) {
        float4 gv = gsh[c + SCH * j];  // conflict-free interleaved map
        v2f bx = {gv.x, gv.x}, by = {gv.y, gv.y};
        v2f bz = {gv.z, gv.z}, bw = {gv.w, gv.w};
#pragma unroll
        for (int k = 0; k < 4; ++k) {
          v2f d = __builtin_elementwise_fma(px[k], bx,
                  __builtin_elementwise_fma(py[k], by,
                  __builtin_elementwise_fma(pz[k], bz, bw)));
          acc[k] += sexp2_v2(d);
        }
      }
    }
  }

  __syncthreads();

#pragma unroll
  for (int k = 0; k < 4; ++k) {
    comb[c * (PPB + 1) + pi + 2 * k]     = acc[k].x * (1.0f / (float)REP);
    comb[c * (PPB + 1) + pi + 2 * k + 1] = acc[k].y * (1.0f / (float)REP);
  }
  __syncthreads();

  {
    const int p = t & 15, g = t >> 4;
    float s = 0.f;
#pragma unroll
    for (int j = 0; j < 8; ++j) s += comb[(g * 8 + j) * (PPB + 1) + p];
    s += __shfl_down(s, 32, 64);
    s += __shfl_down(s, 16, 64);
    if ((t & 63) < 16) wpart[(t >> 6) * 16 + (t & 15)] = s;
  }
  __syncthreads();

  if (t < 16) {
    float s = wpart[t] + wpart[16 + t] + wpart[32 + t] + wpart[48 + t];
    const float* p = pred + ((size_t)(b * NPTS + n0 + t)) * 3;
    float hp2 = 0.5f * (p[0] * p[0] + p[1] * p[1] + p[2] * p[2]);
    float ll = (LN2 * fast_log2(s) - hp2) * INV_COUNT;
#pragma unroll
    for (int off = 8; off > 0; off >>= 1) ll += __shfl_down(ll, off, 16);
    if (t == 0) bsum[blockIdx.x] = ll;
  }
}

__global__ __launch_bounds__(THREADS) void gm_reduce(
    const float* __restrict__ bsum, float* __restrict__ out) {
  const int t = threadIdx.x;
  float v = (bsum[t] + bsum[t + 256]) + (bsum[t + 512] + bsum[t + 768]);
  for (int off = 32; off > 0; off >>= 1) v += __shfl_down(v, off, 64);
  __shared__ float w[4];
  if ((t & 63) == 0) w[t >> 6] = v;
  __syncthreads();
  if (t == 0) out[0] = CONST_TERM - ((w[0] + w[1]) + (w[2] + w[3]));
}

extern "C" void kernel_launch(void* const* d_in, const int* in_sizes, int n_in,
                              void* d_out, int out_size, void* d_ws, size_t ws_size,
                              hipStream_t stream) {
  const float* pred = (const float*)d_in[0];
  const float* gt   = (const float*)d_in[1];
  float* out = (float*)d_out;
  float* bsum = (float*)d_ws;

  gm_main<<<NBLOCKS, THREADS, 0, stream>>>(pred, gt, bsum);
  gm_reduce<<<1, THREADS, 0, stream>>>(bsum, out);
}

// Round 12
// 17.164 us; speedup vs baseline: 4.8299x; 4.8299x over previous
//
#include <hip/hip_runtime.h>
#include <math.h>

// GaussianMixtureLoss: loss = CONST - mean_{b,n}( ln sum_m exp(p·g - |g|²/2) - |p|²/2 )
// B=4, N=4096, M=4096, D=3, SIGMA=1.
// R12: minimal-instruction inner loop. R11 probe showed K1 is VALU-ISSUE
// bound (~80 inst/j-iter, VALUBusy 75%, bank conflicts negligible).
//  - Schraudolph scale+bias FOLDED into staged constants: stage
//    (K*g, BIAS - K/2*|g|^2), K = 2^23*log2(e). The 3-fma dot chain then
//    directly yields the integer-domain Schraudolph value.
//  - underflow max() dropped: data bound |x| < 60 log2 << 126.9 (2x margin).
//  - pure-float v2f fma chain (packable to v_pk_fma_f32); only cvt/bitcast/
//    add are scalar so int ops never break the vector chain.
// Per 2 exps: 3 pk_fma + 2 cvt + 2 add. Structure otherwise = R10.
#define BATCH 4
#define NPTS 4096
#define NMIX 4096
#define THREADS 256
#define PPB 16                // points per block
#define PPT 8                 // points per thread (4x v2f)
#define SCH 128               // mixture lane-pairs per block
#define MSTAGE 2048           // mixtures staged per pass (32 KB)
#define PASSES (NMIX / MSTAGE)
#define MPT (MSTAGE / SCH)    // 16
#define NBLOCKS ((BATCH * NPTS) / PPB)  // 1024

#define LN2 0.6931471805599453f
#define CONST_TERM 0.9189385332046727f  // 0.5*log(2*pi)
#define INV_COUNT (1.0f / (float)(BATCH * NPTS))
// Schraudolph folded constants: K = 2^23*log2(e); BIAS = 2^23*(127-0.0563)
#define SEXP_K    12102203.0f
#define SEXP_BIAS 1.06488094e9f

typedef float v2f __attribute__((ext_vector_type(2)));

__device__ __forceinline__ float fast_log2(float x) {
#if __has_builtin(__builtin_amdgcn_logf)
  return __builtin_amdgcn_logf(x);    // raw v_log_f32 (only 16K of these)
#else
  return log2f(x);
#endif
}

__global__ __launch_bounds__(THREADS) void gm_main(
    const float* __restrict__ pred, const float* __restrict__ gt,
    float* __restrict__ bsum) {
  __shared__ float4 gsh[MSTAGE];   // 32 KB: (K*g, BIAS - K/2*|g|^2)
  __shared__ float wpart[64];      // [4 waves][16 points]
  float* comb = (float*)gsh;       // aliased tail buffer [SCH][PPB+1]

  const int t = threadIdx.x;
  const int b = blockIdx.x >> 8;             // 256 blocks per batch
  const int n0 = (blockIdx.x & 255) * PPB;
  const int c = t >> 1;                      // mixture lane-pair 0..127
  const int pi = (t & 1) * PPT;              // point base 0 or 8

  v2f px[4], py[4], pz[4];
  float accx[4], accy[4];
#pragma unroll
  for (int k = 0; k < 4; ++k) {
    const float* p = pred + ((size_t)(b * NPTS + n0 + pi + 2 * k)) * 3;
    px[k] = (v2f){p[0], p[3]};
    py[k] = (v2f){p[1], p[4]};
    pz[k] = (v2f){p[2], p[5]};
    accx[k] = 0.f;
    accy[k] = 0.f;
  }

  for (int q = 0; q < PASSES; ++q) {
    __syncthreads();
#pragma unroll
    for (int k2 = 0; k2 < MSTAGE / THREADS; ++k2) {
      int s = t + k2 * THREADS;
      const float* g = gt + ((size_t)(b * NMIX + q * MSTAGE + s)) * 3;
      float gx = g[0], gy = g[1], gz = g[2];
      float n2 = fmaf(gx, gx, fmaf(gy, gy, gz * gz));
      gsh[s] = make_float4(SEXP_K * gx, SEXP_K * gy, SEXP_K * gz,
                           fmaf(n2, -0.5f * SEXP_K, SEXP_BIAS));
    }
    __syncthreads();

    const float4* gbase = gsh + c;
#pragma unroll 4
    for (int j = 0; j < MPT; ++j) {
      float4 gv = gbase[SCH * j];  // conflict-free: wave reads 32 consec f4
      v2f bx = {gv.x, gv.x}, by = {gv.y, gv.y};
      v2f bz = {gv.z, gv.z}, bw = {gv.w, gv.w};
#pragma unroll
      for (int k = 0; k < 4; ++k) {
        v2f d = __builtin_elementwise_fma(px[k], bx,
                __builtin_elementwise_fma(py[k], by,
                __builtin_elementwise_fma(pz[k], bz, bw)));
        // Schraudolph: exp ~= bitcast((int)d); d pre-scaled+biased above
        accx[k] += __builtin_bit_cast(float, (int)d.x);
        accy[k] += __builtin_bit_cast(float, (int)d.y);
      }
    }
  }

  __syncthreads();  // all gsh reads done before aliasing as comb

#pragma unroll
  for (int k = 0; k < 4; ++k) {
    comb[c * (PPB + 1) + pi + 2 * k]     = accx[k];
    comb[c * (PPB + 1) + pi + 2 * k + 1] = accy[k];
  }
  __syncthreads();

  {
    const int p = t & 15, g = t >> 4;
    float s = 0.f;
#pragma unroll
    for (int j = 0; j < 8; ++j) s += comb[(g * 8 + j) * (PPB + 1) + p];
    s += __shfl_down(s, 32, 64);
    s += __shfl_down(s, 16, 64);
    if ((t & 63) < 16) wpart[(t >> 6) * 16 + (t & 15)] = s;
  }
  __syncthreads();

  if (t < 16) {
    float s = wpart[t] + wpart[16 + t] + wpart[32 + t] + wpart[48 + t];
    const float* p = pred + ((size_t)(b * NPTS + n0 + t)) * 3;
    float hp2 = 0.5f * (p[0] * p[0] + p[1] * p[1] + p[2] * p[2]);
    float ll = (LN2 * fast_log2(s) - hp2) * INV_COUNT;
#pragma unroll
    for (int off = 8; off > 0; off >>= 1) ll += __shfl_down(ll, off, 16);
    if (t == 0) bsum[blockIdx.x] = ll;
  }
}

__global__ __launch_bounds__(THREADS) void gm_reduce(
    const float* __restrict__ bsum, float* __restrict__ out) {
  const int t = threadIdx.x;
  float v = (bsum[t] + bsum[t + 256]) + (bsum[t + 512] + bsum[t + 768]);
  for (int off = 32; off > 0; off >>= 1) v += __shfl_down(v, off, 64);
  __shared__ float w[4];
  if ((t & 63) == 0) w[t >> 6] = v;
  __syncthreads();
  if (t == 0) out[0] = CONST_TERM - ((w[0] + w[1]) + (w[2] + w[3]));
}

extern "C" void kernel_launch(void* const* d_in, const int* in_sizes, int n_in,
                              void* d_out, int out_size, void* d_ws, size_t ws_size,
                              hipStream_t stream) {
  const float* pred = (const float*)d_in[0];
  const float* gt   = (const float*)d_in[1];
  float* out = (float*)d_out;
  float* bsum = (float*)d_ws;  // 1024 floats, fully overwritten every call

  gm_main<<<NBLOCKS, THREADS, 0, stream>>>(pred, gt, bsum);
  gm_reduce<<<1, THREADS, 0, stream>>>(bsum, out);
}